// Round 1
// baseline (5651.879 us; speedup 1.0000x reference)
//
#include <hip/hip_runtime.h>
#include <math.h>

#define IMG_H 256
#define IMG_W 256
#define NCH   128
#define HID   256
#define TP    64          // pixels per block (one row segment)
#define TPP   68          // padded LDS row stride (floats)
#define CH_CHUNK 8
#define KC    (CH_CHUNK*25)      // 200 K-rows per chunk
#define NCHUNK (NCH/CH_CHUNK)    // 16
#define OMEGA 30.0f

union SMem {
  float A[KC][TPP];      // 200*68*4 = 54.4 KB  (layer-1 staging)
  float Hb[HID][TPP];    // 256*68*4 = 69.6 KB  (hidden activations, reused in place)
};

__global__ __launch_bounds__(256, 2)
void nerd_fused(const float* __restrict__ xi,
                const float* __restrict__ W1, const float* __restrict__ b1,
                const float* __restrict__ W2, const float* __restrict__ b2,
                const float* __restrict__ W3, const float* __restrict__ b3,
                const float* __restrict__ W4, const float* __restrict__ b4,
                float* __restrict__ out)
{
  __shared__ SMem sm;
  const int tid = threadIdx.x;
  const int oq  = tid & 63;   // output-channel quarter: o = 4*oq + q
  const int pg  = tid >> 6;   // pixel group (== wave id), 16 pixels each
  const int blk = blockIdx.x;
  const int y   = blk >> 2;
  const int w0  = (blk & 3) * TP;

  // ---------------- layer 1: z1 = x @ W1 + b1 ----------------
  float acc[16][4];
  {
    const float4 bb = *reinterpret_cast<const float4*>(&b1[4*oq]);
    #pragma unroll
    for (int j=0;j<16;j++){ acc[j][0]=bb.x; acc[j][1]=bb.y; acc[j][2]=bb.z; acc[j][3]=bb.w; }
  }

  for (int chk = 0; chk < NCHUNK; ++chk) {
    const int c0 = chk * CH_CHUNK;
    __syncthreads();
    // stage A[kl][p] = patch feature (zero-padded gather), coalesced along p
    for (int idx = tid; idx < KC*TP; idx += 256) {
      const int p  = idx & 63;
      const int kl = idx >> 6;
      const int c  = kl / 25;
      const int r  = kl - 25*c;
      const int dy = r / 5;
      const int dx = r - 5*dy;
      const int yy = y + dy - 2;
      const int xx = w0 + p + dx - 2;
      float v = 0.f;
      if ((unsigned)yy < 256u && (unsigned)xx < 256u)
        v = xi[(size_t)(c0 + c)*(IMG_H*IMG_W) + yy*IMG_W + xx];
      sm.A[kl][p] = v;
    }
    __syncthreads();
    const float* wr = W1 + (size_t)(c0*25)*HID + 4*oq;
    #pragma unroll 2
    for (int k=0;k<KC;k++){
      const float4 w = *reinterpret_cast<const float4*>(wr + (size_t)k*HID);
      const float* ap = &sm.A[k][pg*16];
      #pragma unroll
      for (int j=0;j<16;j++){
        const float a = ap[j];
        acc[j][0] += a*w.x; acc[j][1] += a*w.y; acc[j][2] += a*w.z; acc[j][3] += a*w.w;
      }
    }
  }
  // coords features (rows 3200, 3201 of W1)
  {
    const float4 wy = *reinterpret_cast<const float4*>(&W1[(size_t)3200*HID + 4*oq]);
    const float4 wx = *reinterpret_cast<const float4*>(&W1[(size_t)3201*HID + 4*oq]);
    const float gy = -1.f + (2.f/255.f)*(float)y;
    #pragma unroll
    for (int j=0;j<16;j++){
      const float gx = -1.f + (2.f/255.f)*(float)(w0 + pg*16 + j);
      acc[j][0] += gy*wy.x + gx*wx.x;
      acc[j][1] += gy*wy.y + gx*wx.y;
      acc[j][2] += gy*wy.z + gx*wx.z;
      acc[j][3] += gy*wy.w + gx*wx.w;
    }
  }
  // h1 = sin(30*z1) -> LDS (aliases A; all reads done)
  __syncthreads();
  #pragma unroll
  for (int q=0;q<4;q++){
    #pragma unroll
    for (int jj=0;jj<4;jj++){
      float4 v;
      v.x = sinf(OMEGA*acc[4*jj+0][q]);
      v.y = sinf(OMEGA*acc[4*jj+1][q]);
      v.z = sinf(OMEGA*acc[4*jj+2][q]);
      v.w = sinf(OMEGA*acc[4*jj+3][q]);
      *reinterpret_cast<float4*>(&sm.Hb[4*oq+q][pg*16 + 4*jj]) = v;
    }
  }
  __syncthreads();

  // ---------------- layers 2 and 3 (in-place ping in LDS) ----------------
  const float* Wmid[2] = {W2, W3};
  const float* bmid[2] = {b2, b3};
  for (int L=0; L<2; ++L) {
    float a2[16][4];
    {
      const float4 bb = *reinterpret_cast<const float4*>(&bmid[L][4*oq]);
      #pragma unroll
      for (int j=0;j<16;j++){ a2[j][0]=bb.x; a2[j][1]=bb.y; a2[j][2]=bb.z; a2[j][3]=bb.w; }
    }
    const float* wr = Wmid[L] + 4*oq;
    #pragma unroll 2
    for (int k=0;k<HID;k++){
      const float4 w = *reinterpret_cast<const float4*>(wr + (size_t)k*HID);
      const float* ap = &sm.Hb[k][pg*16];
      #pragma unroll
      for (int j=0;j<16;j++){
        const float a = ap[j];
        a2[j][0] += a*w.x; a2[j][1] += a*w.y; a2[j][2] += a*w.z; a2[j][3] += a*w.w;
      }
    }
    __syncthreads();   // all reads of Hb complete before overwrite
    #pragma unroll
    for (int q=0;q<4;q++){
      #pragma unroll
      for (int jj=0;jj<4;jj++){
        float4 v;
        v.x = sinf(OMEGA*a2[4*jj+0][q]);
        v.y = sinf(OMEGA*a2[4*jj+1][q]);
        v.z = sinf(OMEGA*a2[4*jj+2][q]);
        v.w = sinf(OMEGA*a2[4*jj+3][q]);
        *reinterpret_cast<float4*>(&sm.Hb[4*oq+q][pg*16 + 4*jj]) = v;
      }
    }
    __syncthreads();
  }

  // ---------------- layer 4: out = h3 @ W4 + b4 ----------------
  {
    const int p = tid & 63;
    const int c = tid >> 6;
    if (c < 3) {
      float s = b4[c];
      #pragma unroll 4
      for (int i=0;i<HID;i++)
        s += sm.Hb[i][p] * W4[i*3 + c];
      out[(size_t)c*(IMG_H*IMG_W) + (size_t)y*IMG_W + w0 + p] = s;
    }
  }
}

extern "C" void kernel_launch(void* const* d_in, const int* in_sizes, int n_in,
                              void* d_out, int out_size, void* d_ws, size_t ws_size,
                              hipStream_t stream) {
  const float* xi = (const float*)d_in[0];
  const float* W1 = (const float*)d_in[1];
  const float* b1 = (const float*)d_in[2];
  const float* W2 = (const float*)d_in[3];
  const float* b2 = (const float*)d_in[4];
  const float* W3 = (const float*)d_in[5];
  const float* b3 = (const float*)d_in[6];
  const float* W4 = (const float*)d_in[7];
  const float* b4 = (const float*)d_in[8];
  float* out = (float*)d_out;

  dim3 grid(65536 / TP);   // 1024 blocks
  dim3 block(256);
  nerd_fused<<<grid, block, 0, stream>>>(xi, W1, b1, W2, b2, W3, b3, W4, b4, out);
}

// Round 2
// 1269.717 us; speedup vs baseline: 4.4513x; 4.4513x over previous
//
#include <hip/hip_runtime.h>
#include <math.h>
#include <stdint.h>

typedef _Float16 f16;
typedef _Float16 f16x8 __attribute__((ext_vector_type(8)));
typedef float f32x4 __attribute__((ext_vector_type(4)));
typedef unsigned short u16;
typedef u16 u16x8 __attribute__((ext_vector_type(8)));

#define HID 256
#define K1ACT 3202
#define NSTAGE1 101           // ceil(3202/32) -> padded K = 3232
#define NSTAGE2 8             // 256/32
#define NPX 65536

// ws layout (bytes)
#define OFF_W1 0
#define SZ_W1  ((size_t)NSTAGE1*32768)   // 3,309,568
#define OFF_W2 SZ_W1
#define SZ_W2  ((size_t)NSTAGE2*32768)   // 262,144
#define OFF_W3 (OFF_W2+SZ_W2)
#define OFF_H  ((size_t)4194304)         // 4 MB
// total need = OFF_H + 65536*256*4 = 71,303,168 B

__device__ inline void split2(float v, u16& h, u16& l){
  f16 hv = (f16)v;                 // RNE
  f16 lv = (f16)(v - (float)hv);   // exact subtract, then RNE
  h = __builtin_bit_cast(u16, hv);
  l = __builtin_bit_cast(u16, lv);
}

// ---------------------------------------------------------------------------
// Pre-split W (fp32 row-major [K][256]) into fp16 hi/lo units in
// MFMA-fragment-major layout:
//   unit(s, w, nf, split, lane) : 8 fp16, j=0..7 = W[s*32 + (lane>>4)*8 + j]
//                                            [w*64 + nf*16 + (lane&15)]
//   offset(units) = (((s*4 + w)*4 + nf)*2 + split)*64 + lane
// Zero-padded for k >= Kact.
// ---------------------------------------------------------------------------
__global__ void prep_w(const float* __restrict__ W, int Kact, int nStages,
                       u16* __restrict__ outp){
  int t = blockIdx.x*256 + threadIdx.x;
  if (t >= nStages*1024) return;
  int s = t >> 10, r = t & 1023;
  int w = r >> 8, nf = (r >> 6) & 3, l = r & 63;
  int col = w*64 + nf*16 + (l & 15);
  int kb  = s*32 + (l >> 4)*8;
  u16x8 hv, lv;
  #pragma unroll
  for (int j = 0; j < 8; ++j){
    int k = kb + j;
    float v = (k < Kact) ? W[(size_t)k*HID + col] : 0.f;
    u16 h, lo; split2(v, h, lo);
    hv[j] = h; lv[j] = lo;
  }
  size_t U0 = ((((size_t)s*4 + w)*4 + nf)*2 + 0)*64 + l;
  *(u16x8*)(outp + U0*8)        = hv;
  *(u16x8*)(outp + (U0+64)*8)   = lv;
}

// ---------------------------------------------------------------------------
// Fused GEMM layer. MODE 0: A = im2col(xi)+coords, out -> h (packed hi|lo u32)
//                   MODE 1: A = h-in,               out -> h
//                   MODE 2: A = h-in,               tail = layer4 -> out (fp32)
// Block = 64 pixels (one row segment), 256 threads = 4 waves.
// Wave w owns cols [w*64, w*64+64). acc = 4x4 frags of 16x16.
// 3 MFMAs per (mf,nf,kstep): hi*hi + lo*hi + hi*lo.
// ---------------------------------------------------------------------------
template<int MODE>
__global__ __launch_bounds__(256, 2)
void gemm_layer(const float* __restrict__ xi,
                const uint32_t* hin,
                const u16* __restrict__ Wp,
                const float* __restrict__ bias,
                uint32_t* hout,
                const float* __restrict__ W4,
                const float* __restrict__ b4,
                float* out,
                int nStages)
{
  __shared__ __align__(16) u16 Bt[16384];  // 32 KB: 32k x 256col hi/lo
  __shared__ __align__(16) u16 At[4096];   // 8 KB:  64px x 32k  hi/lo
  __shared__ float red[4][64][3];          // MODE 2 cross-wave partials

  const int tid  = threadIdx.x;
  const int lane = tid & 63;
  const int wv   = tid >> 6;               // wave id, uniform
  const int pxb  = blockIdx.x * 64;
  const int y    = pxb >> 8;               // all 64 px share one image row
  const int x0   = pxb & 255;

  f32x4 acc[4][4];
  #pragma unroll
  for (int a=0;a<4;a++)
    #pragma unroll
    for (int b=0;b<4;b++) acc[a][b] = f32x4{0.f,0.f,0.f,0.f};

  const float gy = -1.f + (2.f/255.f)*(float)y;
  const float gx = -1.f + (2.f/255.f)*(float)(x0 + lane);

  for (int s = 0; s < nStages; ++s){
    // ---- A staging: thread covers px = lane, k = s*32 + wv*8 + [0..8)
    u16x8 hv, lv;
    if (MODE == 0){
      #pragma unroll
      for (int j=0;j<8;++j){
        int k = s*32 + wv*8 + j;          // wave-uniform
        float v = 0.f;
        if (k < 3200){
          int c  = k/25, rr = k - 25*c;   // uniform
          int dy = rr/5, dx = rr - dy*5;  // uniform
          int yy = y + dy - 2;
          int xx = x0 + lane + dx - 2;
          if ((unsigned)yy < 256u && (unsigned)xx < 256u)
            v = xi[((size_t)c<<16) + ((size_t)yy<<8) + xx];
        } else if (k == 3200) v = gy;
        else if (k == 3201) v = gx;
        u16 h,l; split2(v,h,l); hv[j]=h; lv[j]=l;
      }
    } else {
      const uint32_t* hp = hin + (size_t)(pxb + lane)*HID + s*32 + wv*8;
      uint4 a0 = *(const uint4*)hp;
      uint4 a1 = *(const uint4*)(hp+4);
      uint32_t vs[8] = {a0.x,a0.y,a0.z,a0.w,a1.x,a1.y,a1.z,a1.w};
      #pragma unroll
      for (int j=0;j<8;++j){ hv[j] = (u16)(vs[j] & 0xffffu); lv[j] = (u16)(vs[j]>>16); }
    }
    {
      int mf   = lane >> 4;
      int lidx = wv*16 + (lane & 15);
      *(u16x8*)(At + (size_t)((mf*2+0)*64 + lidx)*8) = hv;
      *(u16x8*)(At + (size_t)((mf*2+1)*64 + lidx)*8) = lv;
    }
    // ---- B staging: 8 x global_load_lds(16B) per wave, fully linear
    {
      const char* src = (const char*)Wp + (size_t)s*32768 + (size_t)wv*8192 + (size_t)lane*16;
      u16* dst = Bt + wv*4096;             // 8 KB per wave
      #pragma unroll
      for (int i=0;i<8;++i){
        __builtin_amdgcn_global_load_lds(
            (const __attribute__((address_space(1))) uint32_t*)(src + i*1024),
            (__attribute__((address_space(3))) uint32_t*)(dst + i*512),
            16, 0, 0);
      }
    }
    __syncthreads();
    // ---- compute one K-step (BK = 32)
    f16x8 ah[4], al[4];
    #pragma unroll
    for (int mf=0;mf<4;++mf){
      ah[mf] = *(const f16x8*)(At + (size_t)((mf*2+0)*64 + lane)*8);
      al[mf] = *(const f16x8*)(At + (size_t)((mf*2+1)*64 + lane)*8);
    }
    #pragma unroll
    for (int nf=0;nf<4;++nf){
      f16x8 bh = *(const f16x8*)(Bt + (size_t)((((wv*4+nf)*2)+0)*64 + lane)*8);
      f16x8 bl = *(const f16x8*)(Bt + (size_t)((((wv*4+nf)*2)+1)*64 + lane)*8);
      #pragma unroll
      for (int mf=0;mf<4;++mf){
        acc[mf][nf] = __builtin_amdgcn_mfma_f32_16x16x32_f16(ah[mf], bh, acc[mf][nf], 0,0,0);
        acc[mf][nf] = __builtin_amdgcn_mfma_f32_16x16x32_f16(al[mf], bh, acc[mf][nf], 0,0,0);
        acc[mf][nf] = __builtin_amdgcn_mfma_f32_16x16x32_f16(ah[mf], bl, acc[mf][nf], 0,0,0);
      }
    }
    __syncthreads();
  }

  // per-lane bias for its 4 column fragments
  float bcol[4];
  #pragma unroll
  for (int nf=0;nf<4;++nf) bcol[nf] = bias[wv*64 + nf*16 + (lane&15)];

  if (MODE != 2){
    // h = sin(30 z) -> split fp16 hi/lo packed u32, plain [px][ch] layout
    #pragma unroll
    for (int mf=0;mf<4;++mf)
      #pragma unroll
      for (int nf=0;nf<4;++nf)
        #pragma unroll
        for (int j=0;j<4;++j){
          float z = acc[mf][nf][j] + bcol[nf];
          float h = sinf(30.f*z);
          u16 hh,ll; split2(h,hh,ll);
          int row = mf*16 + (lane>>4)*4 + j;
          int col = wv*64 + nf*16 + (lane&15);
          hout[(size_t)(pxb+row)*HID + col] = (uint32_t)hh | ((uint32_t)ll<<16);
        }
  } else {
    // fused layer 4: out(px,c) = sum_col sin(30 z3) * W4[col][c] + b4[c]
    float w4v[4][3];
    #pragma unroll
    for (int nf=0;nf<4;++nf){
      int col = wv*64 + nf*16 + (lane&15);
      w4v[nf][0]=W4[col*3+0]; w4v[nf][1]=W4[col*3+1]; w4v[nf][2]=W4[col*3+2];
    }
    #pragma unroll
    for (int mf=0;mf<4;++mf)
      #pragma unroll
      for (int j=0;j<4;++j){
        float s0=0.f,s1=0.f,s2=0.f;
        #pragma unroll
        for (int nf=0;nf<4;++nf){
          float h = sinf(30.f*(acc[mf][nf][j] + bcol[nf]));
          s0 += h*w4v[nf][0]; s1 += h*w4v[nf][1]; s2 += h*w4v[nf][2];
        }
        #pragma unroll
        for (int m=1;m<16;m<<=1){
          s0 += __shfl_xor(s0, m);
          s1 += __shfl_xor(s1, m);
          s2 += __shfl_xor(s2, m);
        }
        if ((lane & 15) == 0){
          int row = mf*16 + (lane>>4)*4 + j;
          red[wv][row][0]=s0; red[wv][row][1]=s1; red[wv][row][2]=s2;
        }
      }
    __syncthreads();
    if (tid < 192){
      int px = tid & 63, c = tid >> 6;
      float v = red[0][px][c]+red[1][px][c]+red[2][px][c]+red[3][px][c] + b4[c];
      out[(size_t)c*NPX + pxb + px] = v;
    }
  }
}

// ---------------------------------------------------------------------------
extern "C" void kernel_launch(void* const* d_in, const int* in_sizes, int n_in,
                              void* d_out, int out_size, void* d_ws, size_t ws_size,
                              hipStream_t stream) {
  const float* xi = (const float*)d_in[0];
  const float* W1 = (const float*)d_in[1];
  const float* b1 = (const float*)d_in[2];
  const float* W2 = (const float*)d_in[3];
  const float* b2 = (const float*)d_in[4];
  const float* W3 = (const float*)d_in[5];
  const float* b3 = (const float*)d_in[6];
  const float* W4 = (const float*)d_in[7];
  const float* b4 = (const float*)d_in[8];
  float* out = (float*)d_out;

  char* ws = (char*)d_ws;
  u16* W1p = (u16*)(ws + OFF_W1);
  u16* W2p = (u16*)(ws + OFF_W2);
  u16* W3p = (u16*)(ws + OFF_W3);
  uint32_t* h = (uint32_t*)(ws + OFF_H);

  prep_w<<<NSTAGE1*4, 256, 0, stream>>>(W1, K1ACT, NSTAGE1, W1p);  // 404 blocks
  prep_w<<<NSTAGE2*4, 256, 0, stream>>>(W2, HID, NSTAGE2, W2p);
  prep_w<<<NSTAGE2*4, 256, 0, stream>>>(W3, HID, NSTAGE2, W3p);

  dim3 grid(NPX/64), block(256);
  gemm_layer<0><<<grid, block, 0, stream>>>(xi, nullptr, W1p, b1, h,
                                            nullptr, nullptr, nullptr, NSTAGE1);
  gemm_layer<1><<<grid, block, 0, stream>>>(nullptr, h, W2p, b2, h,
                                            nullptr, nullptr, nullptr, NSTAGE2);
  gemm_layer<2><<<grid, block, 0, stream>>>(nullptr, h, W3p, b3, nullptr,
                                            W4, b4, out, NSTAGE2);
}